// Round 3
// baseline (1664.038 us; speedup 1.0000x reference)
//
#include <hip/hip_runtime.h>
#include <hip/hip_bf16.h>
#include <math.h>

// B=16,S=1024 -> M=16384 tokens; D=1024, F=4096, E=8, R=32, SCALING=0.5
// Inputs/outputs fp32 (reference dtypes). MFMA compute in bf16 (fp32->bf16 RNE
// conversion during staging). Outputs concat: out[M*D], routing[M*E], ec[M*E].

#define M_TOK 16384
#define DIM_D 1024
#define DIM_F 4096
#define NEXP 8
#define RANK 32
#define NER 256  // NEXP*RANK

typedef __attribute__((ext_vector_type(8))) short bf16x8;
typedef __attribute__((ext_vector_type(4))) float f32x4;

__device__ inline short f2bs(float x) {
  __hip_bfloat16 h = __float2bfloat16(x);
  return *reinterpret_cast<short*>(&h);
}

__device__ inline bf16x8 ld8(const float* p) {
  const float4* q = (const float4*)p;
  float4 u = q[0], v = q[1];
  bf16x8 r;
  r[0] = f2bs(u.x); r[1] = f2bs(u.y); r[2] = f2bs(u.z); r[3] = f2bs(u.w);
  r[4] = f2bs(v.x); r[5] = f2bs(v.y); r[6] = f2bs(v.z); r[7] = f2bs(v.w);
  return r;
}
__device__ inline bf16x8 ld8(const short* p) { return *(const bf16x8*)p; }

// ---------------- K0: router (one wave per token, fp32) ----------------
__global__ __launch_bounds__(256) void router_kernel(
    const float* __restrict__ X,     // [M, D]
    const float* __restrict__ RW,    // [E, D]
    const float* __restrict__ RB,    // [E]
    float* __restrict__ routing_out, // [M, E]
    float* __restrict__ ec_out,      // [M, E]
    int* __restrict__ idx_out)       // [M]
{
  const int wave = threadIdx.x >> 6;
  const int lane = threadIdx.x & 63;
  const int t = blockIdx.x * 4 + wave;

  const float4* xp = (const float4*)(X + (size_t)t * DIM_D);
  float4 xv[4];
#pragma unroll
  for (int i = 0; i < 4; ++i) xv[i] = xp[lane + 64 * i];

  float logit[NEXP];
#pragma unroll
  for (int e = 0; e < NEXP; ++e) {
    const float4* wp = (const float4*)(RW + (size_t)e * DIM_D);
    double p = 0.0;
#pragma unroll
    for (int i = 0; i < 4; ++i) {
      float4 w = wp[lane + 64 * i];
      p += (double)xv[i].x * w.x + (double)xv[i].y * w.y +
           (double)xv[i].z * w.z + (double)xv[i].w * w.w;
    }
#pragma unroll
    for (int off = 32; off > 0; off >>= 1) p += __shfl_xor(p, off);
    logit[e] = (float)p + RB[e];
  }
  float m = logit[0];
  int am = 0;
#pragma unroll
  for (int e = 1; e < NEXP; ++e)
    if (logit[e] > m) { m = logit[e]; am = e; }
  float pr[NEXP], s = 0.f;
#pragma unroll
  for (int e = 0; e < NEXP; ++e) { pr[e] = expf(logit[e] - m); s += pr[e]; }
  const float inv = 1.f / s;
  if (lane < NEXP) {
    float r = pr[lane] * inv;
    routing_out[(size_t)t * NEXP + lane] = r;
    float y = (lane == am) ? 1.f : 0.f;
    ec_out[(size_t)t * NEXP + lane] = (y - r) + r;
  }
  if (lane == 0) idx_out[t] = am;
}

// ---------------- unified MFMA GEMM C = A * Bm^T ----------------
// A [M,KMAIN] (fp32 or bf16), Bm [N,KMAIN] fp32. Optional LoRA K-extension
// (G2 [M,256] bf16, LW [E,N,32] fp32). 128x128 tile, 4 waves, 4x4
// mfma_f32_16x16x32_bf16 per wave.
// EPI: 0 = fp32 out, +bias+0.5*LB[e]   (final out)
//      1 = bf16 out, gelu(+bias+0.5*LB[e])  (a_ws)
//      2 = bf16 out, mask-by-idx 0.5*(acc+bias)  (LoRA-A -> g2)
template <int KMAIN, int DO_LORA, int EPI, typename TA>
__global__ __launch_bounds__(256, 2) void gemm_fused(
    const TA* __restrict__ A, const float* __restrict__ Bm,
    const short* __restrict__ G2, const float* __restrict__ LW,
    const float* __restrict__ LB, const float* __restrict__ bias,
    const int* __restrict__ idx, void* __restrict__ outv, int N)
{
  __shared__ __align__(16) short As[128 * 32];
  __shared__ __align__(16) short Bs[128 * 32];

  const int tid = threadIdx.x;
  const int m0 = blockIdx.y * 128;
  const int n0 = blockIdx.x * 128;
  const int lane = tid & 63;
  const int wv = tid >> 6;
  const int quad = lane >> 4;
  const int lrow = lane & 15;
  const int wr = wv >> 1;
  const int wc = wv & 1;
  const int r0 = tid >> 2;       // staging row 0..63
  const int c4 = (tid & 3) * 8;  // staging elem offset within 32-chunk

  f32x4 acc[4][4];
#pragma unroll
  for (int i = 0; i < 4; ++i)
#pragma unroll
    for (int j = 0; j < 4; ++j) acc[i][j] = (f32x4){0.f, 0.f, 0.f, 0.f};

  constexpr int IT_MAIN = KMAIN / 32;
  constexpr int IT_TOT = IT_MAIN + (DO_LORA ? NEXP : 0);
  for (int it = 0; it < IT_TOT; ++it) {
    bf16x8 ra0, ra1, rb0, rb1;
    if (!DO_LORA || it < IT_MAIN) {
      const int k = it * 32;
      const TA* a0 = A + (size_t)(m0 + r0) * KMAIN + k + c4;
      ra0 = ld8(a0);
      ra1 = ld8(a0 + (size_t)64 * KMAIN);
      const float* b0 = Bm + (size_t)(n0 + r0) * KMAIN + k + c4;
      rb0 = ld8(b0);
      rb1 = ld8(b0 + (size_t)64 * KMAIN);
    } else {
      const int e = it - IT_MAIN;
      const short* a0 = G2 + (size_t)(m0 + r0) * NER + e * RANK + c4;
      ra0 = ld8(a0);
      ra1 = ld8(a0 + 64 * NER);
      const float* b0 = LW + ((size_t)e * N + n0 + r0) * RANK + c4;
      rb0 = ld8(b0);
      rb1 = ld8(b0 + 64 * RANK);
    }
    __syncthreads();  // previous iteration's LDS reads done
    *(bf16x8*)&As[tid * 8] = ra0;
    *(bf16x8*)&As[2048 + tid * 8] = ra1;
    *(bf16x8*)&Bs[tid * 8] = rb0;
    *(bf16x8*)&Bs[2048 + tid * 8] = rb1;
    __syncthreads();  // tile visible

    bf16x8 af[4], bfv[4];
#pragma unroll
    for (int i = 0; i < 4; ++i)
      af[i] = *(const bf16x8*)&As[(wr * 64 + i * 16 + lrow) * 32 + quad * 8];
#pragma unroll
    for (int j = 0; j < 4; ++j)
      bfv[j] = *(const bf16x8*)&Bs[(wc * 64 + j * 16 + lrow) * 32 + quad * 8];
#pragma unroll
    for (int i = 0; i < 4; ++i)
#pragma unroll
      for (int j = 0; j < 4; ++j)
        acc[i][j] = __builtin_amdgcn_mfma_f32_16x16x32_bf16(af[i], bfv[j],
                                                            acc[i][j], 0, 0, 0);
  }

  float cb[4];
#pragma unroll
  for (int j = 0; j < 4; ++j) cb[j] = bias[n0 + wc * 64 + j * 16 + lrow];

#pragma unroll
  for (int i = 0; i < 4; ++i) {
#pragma unroll
    for (int reg = 0; reg < 4; ++reg) {
      const int t = m0 + wr * 64 + i * 16 + quad * 4 + reg;
      const int e = idx[t];
#pragma unroll
      for (int j = 0; j < 4; ++j) {
        const int gc = n0 + wc * 64 + j * 16 + lrow;
        float v = acc[i][j][reg];
        if (EPI == 2) {
          v = ((gc >> 5) == e) ? 0.5f * (v + cb[j]) : 0.f;
          ((short*)outv)[(size_t)t * N + gc] = f2bs(v);
        } else {
          v += cb[j] + 0.5f * LB[(size_t)e * N + gc];
          if (EPI == 1) {
            v = 0.5f * v * (1.0f + erff(v * 0.70710678118654752f));
            ((short*)outv)[(size_t)t * N + gc] = f2bs(v);
          } else {
            ((float*)outv)[(size_t)t * N + gc] = v;
          }
        }
      }
    }
  }
}

extern "C" void kernel_launch(void* const* d_in, const int* in_sizes, int n_in,
                              void* d_out, int out_size, void* d_ws, size_t ws_size,
                              hipStream_t stream) {
  (void)in_sizes; (void)n_in; (void)out_size; (void)ws_size;
  const float* x        = (const float*)d_in[0];
  const float* router_w = (const float*)d_in[1];
  const float* router_b = (const float*)d_in[2];
  const float* fc1_w    = (const float*)d_in[3];
  const float* fc1_b    = (const float*)d_in[4];
  const float* fc2_w    = (const float*)d_in[5];
  const float* fc2_b    = (const float*)d_in[6];
  const float* down_A_w = (const float*)d_in[7];   // [E,R,D] = [256, 1024]
  const float* down_A_b = (const float*)d_in[8];   // [E*R] = [256]
  const float* down_B_w = (const float*)d_in[9];   // [E,F,R]
  const float* down_B_b = (const float*)d_in[10];  // [E,F]
  const float* up_A_w   = (const float*)d_in[11];  // [E,R,F] = [256, 4096]
  const float* up_A_b   = (const float*)d_in[12];  // [256]
  const float* up_B_w   = (const float*)d_in[13];  // [E,D,R]
  const float* up_B_b   = (const float*)d_in[14];  // [E,D]

  // workspace: idx | g2d | g2u | a_ws
  char* ws = (char*)d_ws;
  int* idxp = (int*)ws;                        // 64 KiB
  size_t off = (size_t)M_TOK * sizeof(int);
  short* g2d = (short*)(ws + off);             // M*256 bf16 = 8 MiB
  off += (size_t)M_TOK * NER * 2;
  short* g2u = (short*)(ws + off);             // 8 MiB
  off += (size_t)M_TOK * NER * 2;
  short* a_ws = (short*)(ws + off);            // M*F bf16 = 128 MiB

  float* out = (float*)d_out;
  float* routing = out + (size_t)M_TOK * DIM_D;
  float* ec = routing + (size_t)M_TOK * NEXP;

  router_kernel<<<M_TOK / 4, 256, 0, stream>>>(x, router_w, router_b, routing,
                                               ec, idxp);
  // LoRA-A down: h_all = x . down_A_w^T, masked by idx -> g2d [M,256] bf16
  gemm_fused<DIM_D, 0, 2, float><<<dim3(NER / 128, M_TOK / 128), 256, 0,
                                   stream>>>(
      x, down_A_w, nullptr, nullptr, nullptr, down_A_b, idxp, g2d, NER);
  // GEMM1: a_ws = gelu(x . fc1_w^T + fc1_b + LoRA-B(down))
  gemm_fused<DIM_D, 1, 1, float><<<dim3(DIM_F / 128, M_TOK / 128), 256, 0,
                                   stream>>>(
      x, fc1_w, g2d, down_B_w, down_B_b, fc1_b, idxp, a_ws, DIM_F);
  // LoRA-A up: h_all = a . up_A_w^T, masked -> g2u [M,256] bf16
  gemm_fused<DIM_F, 0, 2, short><<<dim3(NER / 128, M_TOK / 128), 256, 0,
                                   stream>>>(
      a_ws, up_A_w, nullptr, nullptr, nullptr, up_A_b, idxp, g2u, NER);
  // GEMM2: out = a . fc2_w^T + fc2_b + LoRA-B(up)  (fp32 out)
  gemm_fused<DIM_F, 1, 0, short><<<dim3(DIM_D / 128, M_TOK / 128), 256, 0,
                                   stream>>>(
      a_ws, fc2_w, g2u, up_B_w, up_B_b, fc2_b, idxp, out, DIM_D);
}

// Round 4
// 767.635 us; speedup vs baseline: 2.1677x; 2.1677x over previous
//
#include <hip/hip_runtime.h>
#include <hip/hip_bf16.h>
#include <math.h>

// B=16,S=1024 -> M=16384 tokens; D=1024, F=4096, E=8, R=32, SCALING=0.5
// Inputs/outputs fp32. MFMA compute in bf16: all weight/activation tensors
// pre-converted fp32->bf16 (RNE) in workspace, then m97-style async GEMMs.

#define M_TOK 16384
#define DIM_D 1024
#define DIM_F 4096
#define NEXP 8
#define RANK 32
#define NER 256  // NEXP*RANK

typedef __attribute__((ext_vector_type(8))) short bf16x8;
typedef __attribute__((ext_vector_type(4))) float f32x4;

__device__ inline short f2bs(float x) {
  __hip_bfloat16 h = __float2bfloat16(x);
  return *reinterpret_cast<short*>(&h);
}

__device__ inline void async16(const void* g, void* l) {
  __builtin_amdgcn_global_load_lds(
      (__attribute__((address_space(1))) void*)(g),
      (__attribute__((address_space(3))) void*)(l), 16, 0, 0);
}

// ---------------- K_conv: fp32 -> bf16, 8 elems/thread ----------------
__global__ __launch_bounds__(256) void convert_bf16(
    const float* __restrict__ in, short* __restrict__ out, int n8)
{
  const int i = blockIdx.x * 256 + threadIdx.x;
  if (i >= n8) return;
  const float4* p = (const float4*)in + 2 * (size_t)i;
  float4 u = p[0], v = p[1];
  bf16x8 r;
  r[0] = f2bs(u.x); r[1] = f2bs(u.y); r[2] = f2bs(u.z); r[3] = f2bs(u.w);
  r[4] = f2bs(v.x); r[5] = f2bs(v.y); r[6] = f2bs(v.z); r[7] = f2bs(v.w);
  *(bf16x8*)(out + 8 * (size_t)i) = r;
}

// ---------------- K0: router (one wave per token, fp32) ----------------
__global__ __launch_bounds__(256) void router_kernel(
    const float* __restrict__ X,     // [M, D]
    const float* __restrict__ RW,    // [E, D]
    const float* __restrict__ RB,    // [E]
    float* __restrict__ routing_out, // [M, E]
    float* __restrict__ ec_out,      // [M, E]
    int* __restrict__ idx_out)       // [M]
{
  const int wave = threadIdx.x >> 6;
  const int lane = threadIdx.x & 63;
  const int t = blockIdx.x * 4 + wave;

  const float4* xp = (const float4*)(X + (size_t)t * DIM_D);
  float4 xv[4];
#pragma unroll
  for (int i = 0; i < 4; ++i) xv[i] = xp[lane + 64 * i];

  float logit[NEXP];
#pragma unroll
  for (int e = 0; e < NEXP; ++e) {
    const float4* wp = (const float4*)(RW + (size_t)e * DIM_D);
    double p = 0.0;
#pragma unroll
    for (int i = 0; i < 4; ++i) {
      float4 w = wp[lane + 64 * i];
      p += (double)xv[i].x * w.x + (double)xv[i].y * w.y +
           (double)xv[i].z * w.z + (double)xv[i].w * w.w;
    }
#pragma unroll
    for (int off = 32; off > 0; off >>= 1) p += __shfl_xor(p, off);
    logit[e] = (float)p + RB[e];
  }
  float m = logit[0];
  int am = 0;
#pragma unroll
  for (int e = 1; e < NEXP; ++e)
    if (logit[e] > m) { m = logit[e]; am = e; }
  float pr[NEXP], s = 0.f;
#pragma unroll
  for (int e = 0; e < NEXP; ++e) { pr[e] = expf(logit[e] - m); s += pr[e]; }
  const float inv = 1.f / s;
  if (lane < NEXP) {
    float r = pr[lane] * inv;
    routing_out[(size_t)t * NEXP + lane] = r;
    float y = (lane == am) ? 1.f : 0.f;
    ec_out[(size_t)t * NEXP + lane] = (y - r) + r;
  }
  if (lane == 0) idx_out[t] = am;
}

// ---------------- unified bf16 MFMA GEMM C = A * Bm^T ----------------
// A [M,KMAIN] bf16, Bm [N,KMAIN] bf16; optional LoRA K-extension
// (G2 [M,256] bf16, LW [E,N,32] bf16). 128x128 tile, 4 waves, 4x4
// mfma_f32_16x16x32_bf16 per wave, global_load_lds width-16 staging (m97).
// EPI: 0 = fp32 out, +bias+0.5*LB[e]         (final out)
//      1 = bf16 out, gelu(+bias+0.5*LB[e])   (a_ws)
//      2 = bf16 out, mask-by-idx 0.5*(acc+bias)  (LoRA-A -> g2)
template <int KMAIN, int DO_LORA, int EPI>
__global__ __launch_bounds__(256, 2) void gemm_bf16(
    const short* __restrict__ A, const short* __restrict__ Bm,
    const short* __restrict__ G2, const short* __restrict__ LW,
    const float* __restrict__ LB, const float* __restrict__ bias,
    const int* __restrict__ idx, void* __restrict__ outv, int N)
{
  __shared__ __align__(16) short As[128 * 32];
  __shared__ __align__(16) short Bs[128 * 32];

  const int tid = threadIdx.x;
  const int m0 = blockIdx.y * 128;
  const int n0 = blockIdx.x * 128;
  const int lane = tid & 63;
  const int wv = tid >> 6;
  const int quad = lane >> 4;
  const int lrow = lane & 15;
  const int wr = wv >> 1;
  const int wc = wv & 1;
  const int r0 = tid >> 2;       // staging row 0..63
  const int c4 = (tid & 3) * 8;  // staging elem offset within 32-chunk

  f32x4 acc[4][4];
#pragma unroll
  for (int i = 0; i < 4; ++i)
#pragma unroll
    for (int j = 0; j < 4; ++j) acc[i][j] = (f32x4){0.f, 0.f, 0.f, 0.f};

  constexpr int IT_MAIN = KMAIN / 32;
  constexpr int IT_TOT = IT_MAIN + (DO_LORA ? NEXP : 0);
  for (int it = 0; it < IT_TOT; ++it) {
    const short *a0, *a1, *b0, *b1;
    if (!DO_LORA || it < IT_MAIN) {
      const int k = it * 32;
      a0 = A + (size_t)(m0 + r0) * KMAIN + k + c4;
      a1 = a0 + (size_t)64 * KMAIN;
      b0 = Bm + (size_t)(n0 + r0) * KMAIN + k + c4;
      b1 = b0 + (size_t)64 * KMAIN;
    } else {
      const int e = it - IT_MAIN;
      a0 = G2 + (size_t)(m0 + r0) * NER + e * RANK + c4;
      a1 = a0 + 64 * NER;
      b0 = LW + ((size_t)e * N + n0 + r0) * RANK + c4;
      b1 = b0 + 64 * RANK;
    }
    async16(a0, &As[tid * 8]);
    async16(a1, &As[2048 + tid * 8]);
    async16(b0, &Bs[tid * 8]);
    async16(b1, &Bs[2048 + tid * 8]);
    __syncthreads();  // drain async copies; tile visible

    bf16x8 af[4], bfv[4];
#pragma unroll
    for (int i = 0; i < 4; ++i)
      af[i] = *(const bf16x8*)&As[(wr * 64 + i * 16 + lrow) * 32 + quad * 8];
#pragma unroll
    for (int j = 0; j < 4; ++j)
      bfv[j] = *(const bf16x8*)&Bs[(wc * 64 + j * 16 + lrow) * 32 + quad * 8];
#pragma unroll
    for (int i = 0; i < 4; ++i)
#pragma unroll
      for (int j = 0; j < 4; ++j)
        acc[i][j] = __builtin_amdgcn_mfma_f32_16x16x32_bf16(af[i], bfv[j],
                                                            acc[i][j], 0, 0, 0);
    __syncthreads();  // LDS reads done before next overwrite
  }

  float cb[4];
#pragma unroll
  for (int j = 0; j < 4; ++j) cb[j] = bias[n0 + wc * 64 + j * 16 + lrow];

#pragma unroll
  for (int i = 0; i < 4; ++i) {
#pragma unroll
    for (int reg = 0; reg < 4; ++reg) {
      const int t = m0 + wr * 64 + i * 16 + quad * 4 + reg;
      const int e = idx[t];
#pragma unroll
      for (int j = 0; j < 4; ++j) {
        const int gc = n0 + wc * 64 + j * 16 + lrow;
        float v = acc[i][j][reg];
        if (EPI == 2) {
          v = ((gc >> 5) == e) ? 0.5f * (v + cb[j]) : 0.f;
          ((short*)outv)[(size_t)t * N + gc] = f2bs(v);
        } else {
          v += cb[j] + 0.5f * LB[(size_t)e * N + gc];
          if (EPI == 1) {
            v = 0.5f * v * (1.0f + erff(v * 0.70710678118654752f));
            ((short*)outv)[(size_t)t * N + gc] = f2bs(v);
          } else {
            ((float*)outv)[(size_t)t * N + gc] = v;
          }
        }
      }
    }
  }
}

extern "C" void kernel_launch(void* const* d_in, const int* in_sizes, int n_in,
                              void* d_out, int out_size, void* d_ws, size_t ws_size,
                              hipStream_t stream) {
  (void)in_sizes; (void)n_in; (void)out_size; (void)ws_size;
  const float* x        = (const float*)d_in[0];
  const float* router_w = (const float*)d_in[1];
  const float* router_b = (const float*)d_in[2];
  const float* fc1_w    = (const float*)d_in[3];
  const float* fc1_b    = (const float*)d_in[4];
  const float* fc2_w    = (const float*)d_in[5];
  const float* fc2_b    = (const float*)d_in[6];
  const float* down_A_w = (const float*)d_in[7];   // [E,R,D]
  const float* down_A_b = (const float*)d_in[8];   // [E*R]
  const float* down_B_w = (const float*)d_in[9];   // [E,F,R]
  const float* down_B_b = (const float*)d_in[10];  // [E,F]
  const float* up_A_w   = (const float*)d_in[11];  // [E,R,F]
  const float* up_A_b   = (const float*)d_in[12];  // [E*R]
  const float* up_B_w   = (const float*)d_in[13];  // [E,D,R]
  const float* up_B_b   = (const float*)d_in[14];  // [E,D]

  // workspace: idx | g2d | g2u | a_ws | xb | fc1b | fc2b | dAb | uAb | dBb | uBb
  char* ws = (char*)d_ws;
  size_t off = 0;
  int* idxp = (int*)ws;                    off += (size_t)M_TOK * 4;
  short* g2d  = (short*)(ws + off);        off += (size_t)M_TOK * NER * 2;
  short* g2u  = (short*)(ws + off);        off += (size_t)M_TOK * NER * 2;
  short* a_ws = (short*)(ws + off);        off += (size_t)M_TOK * DIM_F * 2;
  short* xb   = (short*)(ws + off);        off += (size_t)M_TOK * DIM_D * 2;
  short* fc1b = (short*)(ws + off);        off += (size_t)DIM_F * DIM_D * 2;
  short* fc2b = (short*)(ws + off);        off += (size_t)DIM_D * DIM_F * 2;
  short* dAb  = (short*)(ws + off);        off += (size_t)NER * DIM_D * 2;
  short* uAb  = (short*)(ws + off);        off += (size_t)NER * DIM_F * 2;
  short* dBb  = (short*)(ws + off);        off += (size_t)NEXP * DIM_F * RANK * 2;
  short* uBb  = (short*)(ws + off);        off += (size_t)NEXP * DIM_D * RANK * 2;

  float* out = (float*)d_out;
  float* routing = out + (size_t)M_TOK * DIM_D;
  float* ec = routing + (size_t)M_TOK * NEXP;

  // fp32 -> bf16 conversions
  auto conv = [&](const float* src, short* dst, size_t n) {
    int n8 = (int)(n / 8);
    convert_bf16<<<(n8 + 255) / 256, 256, 0, stream>>>(src, dst, n8);
  };
  conv(x, xb, (size_t)M_TOK * DIM_D);
  conv(fc1_w, fc1b, (size_t)DIM_F * DIM_D);
  conv(fc2_w, fc2b, (size_t)DIM_D * DIM_F);
  conv(down_A_w, dAb, (size_t)NER * DIM_D);
  conv(up_A_w, uAb, (size_t)NER * DIM_F);
  conv(down_B_w, dBb, (size_t)NEXP * DIM_F * RANK);
  conv(up_B_w, uBb, (size_t)NEXP * DIM_D * RANK);

  router_kernel<<<M_TOK / 4, 256, 0, stream>>>(x, router_w, router_b, routing,
                                               ec, idxp);
  // LoRA-A down: g2d = mask(0.5*(xb . dAb^T + b)) [M,256] bf16
  gemm_bf16<DIM_D, 0, 2><<<dim3(NER / 128, M_TOK / 128), 256, 0, stream>>>(
      xb, dAb, nullptr, nullptr, nullptr, down_A_b, idxp, g2d, NER);
  // GEMM1: a_ws = gelu(xb . fc1b^T + fc1_b + LoRA-B(down))
  gemm_bf16<DIM_D, 1, 1><<<dim3(DIM_F / 128, M_TOK / 128), 256, 0, stream>>>(
      xb, fc1b, g2d, dBb, down_B_b, fc1_b, idxp, a_ws, DIM_F);
  // LoRA-A up: g2u = mask(0.5*(a_ws . uAb^T + b)) [M,256] bf16
  gemm_bf16<DIM_F, 0, 2><<<dim3(NER / 128, M_TOK / 128), 256, 0, stream>>>(
      a_ws, uAb, nullptr, nullptr, nullptr, up_A_b, idxp, g2u, NER);
  // GEMM2: out = a_ws . fc2b^T + fc2_b + LoRA-B(up)  (fp32 out)
  gemm_bf16<DIM_F, 1, 0><<<dim3(DIM_D / 128, M_TOK / 128), 256, 0, stream>>>(
      a_ws, fc2b, g2u, uBb, up_B_b, fc2_b, idxp, out, DIM_D);
}